// Round 15
// baseline (504.901 us; speedup 1.0000x reference)
//
#include <hip/hip_runtime.h>
#include <hip/hip_bf16.h>

typedef __attribute__((ext_vector_type(8))) short bf16x8;
typedef __attribute__((ext_vector_type(4))) float f32x4;
typedef unsigned short ushort_t;
typedef unsigned int uint_t;

#define AS1 __attribute__((address_space(1)))
#define AS3 __attribute__((address_space(3)))

__constant__ int P4tab[16] = {0, 5, 10, 15, 1, 4, 11, 14, 2, 7, 8, 13, 3, 6, 9, 12};

__device__ __forceinline__ void gload_lds16(const void* g, void* l) {
    __builtin_amdgcn_global_load_lds((const AS1 void*)g, (AS3 void*)l, 16, 0, 0);
}

__device__ __forceinline__ ushort_t f2b(float f) {
    unsigned u = __builtin_bit_cast(unsigned, f);
    unsigned r = (u + 0x7FFFu + ((u >> 16) & 1u)) >> 16;
    return (ushort_t)r;
}

// ---------------- convert x (fp32 -> bf16) ----------------
__global__ __launch_bounds__(256) void convert_x_kernel(const float* __restrict__ in,
                                                        ushort_t* __restrict__ out, int n4) {
    int i = blockIdx.x * blockDim.x + threadIdx.x;
    if (i < n4) {
        float4 f = ((const float4*)in)[i];
        ushort4 u;
        u.x = f2b(f.x); u.y = f2b(f.y); u.z = f2b(f.z); u.w = f2b(f.w);
        ((ushort4*)out)[i] = u;
    }
}

// ---------------- transpose+convert ALL weights in one launch ----------------
__global__ __launch_bounds__(256) void transpose_w4_kernel(const float* __restrict__ W0,
                                                           const float* __restrict__ W1,
                                                           const float* __restrict__ W2,
                                                           const float* __restrict__ W3,
                                                           ushort_t* __restrict__ WTqkv,
                                                           ushort_t* __restrict__ WTo) {
    __shared__ float t[32][33];
    int which = blockIdx.z;
    const float* W = (which == 0) ? W0 : (which == 1) ? W1 : (which == 2) ? W2 : W3;
    ushort_t* WT = (which < 3) ? (WTqkv + (size_t)which * 1024 * 1024) : WTo;
    int n0 = blockIdx.x * 32, k0 = blockIdx.y * 32;
    int tx = threadIdx.x, ty = threadIdx.y; // block (32,8)
    for (int i = 0; i < 4; ++i)
        t[ty + i * 8][tx] = W[(size_t)(k0 + ty + i * 8) * 1024 + n0 + tx];
    __syncthreads();
    for (int i = 0; i < 4; ++i)
        WT[(size_t)(n0 + ty + i * 8) * 1024 + k0 + tx] = f2b(t[tx][ty + i * 8]);
}

// ---------------- bf16 MFMA GEMM: 3-slot ring, 2-deep prefetch, counted vmcnt ----------------
template <int N, int OUT_BF16>
__global__ __launch_bounds__(256) void gemm_kernel(const ushort_t* __restrict__ A,
                                                   const ushort_t* __restrict__ BT,
                                                   ushort_t* __restrict__ Cb,
                                                   float* __restrict__ Cf,
                                                   const float* __restrict__ bias) {
    const int K = 1024;
    __shared__ ushort_t As[3 * 128 * 32];
    __shared__ ushort_t Bs[3 * 128 * 32];
    int tid = threadIdx.x;
    int wid = tid >> 6, lane = tid & 63;
    int g = lane >> 4, lr = lane & 15;

    int zz = (int)blockIdx.x + 64 * (int)blockIdx.y;
    int nwg = 64 * (int)gridDim.y;
    int zs = (zz & 7) * (nwg >> 3) + (zz >> 3);
    int m0 = (zs % 64) * 128, n0 = (zs / 64) * 128;

    int wm = wid >> 1, wn = wid & 1;

    f32x4 acc[4][4] = {};

    int c0 = wid * 2;
    int lrow = lane >> 2;
    int lcol = ((lane & 3) ^ ((lane >> 3) & 3)) * 8;
    const ushort_t* Ag0 = A  + (size_t)(m0 + c0 * 16 + lrow) * K + lcol;
    const ushort_t* Ag1 = A  + (size_t)(m0 + c0 * 16 + 16 + lrow) * K + lcol;
    const ushort_t* Bg0 = BT + (size_t)(n0 + c0 * 16 + lrow) * K + lcol;
    const ushort_t* Bg1 = BT + (size_t)(n0 + c0 * 16 + 16 + lrow) * K + lcol;

    int swzA = ((lr >> 1) & 3) << 4;

    auto stage = [&](int si, int kt) {
        char* a0 = (char*)As + si * 8192 + c0 * 1024;
        char* b0 = (char*)Bs + si * 8192 + c0 * 1024;
        gload_lds16(Ag0 + kt * 32, a0);
        gload_lds16(Ag1 + kt * 32, a0 + 1024);
        gload_lds16(Bg0 + kt * 32, b0);
        gload_lds16(Bg1 + kt * 32, b0 + 1024);
    };

    stage(0, 0);
    stage(1, 1);
    asm volatile("s_waitcnt vmcnt(4)" ::: "memory");
    __builtin_amdgcn_s_barrier();
    __builtin_amdgcn_sched_barrier(0);
    for (int kt = 0; kt < 32; ++kt) {
        int nt = kt + 2;
        stage(nt % 3, nt < 32 ? nt : 31);
        const char* ab = (const char*)As + (kt % 3) * 8192;
        const char* bb = (const char*)Bs + (kt % 3) * 8192;
        bf16x8 af[4], bfr[4];
#pragma unroll
        for (int m = 0; m < 4; ++m) {
            int row = wm * 64 + m * 16 + lr;
            af[m] = *(const bf16x8*)(ab + row * 64 + ((g * 16) ^ swzA));
        }
#pragma unroll
        for (int n = 0; n < 4; ++n) {
            int row = wn * 64 + n * 16 + lr;
            bfr[n] = *(const bf16x8*)(bb + row * 64 + ((g * 16) ^ swzA));
        }
#pragma unroll
        for (int m = 0; m < 4; ++m)
#pragma unroll
            for (int n = 0; n < 4; ++n)
                acc[m][n] = __builtin_amdgcn_mfma_f32_16x16x32_bf16(af[m], bfr[n], acc[m][n], 0, 0, 0);
        asm volatile("s_waitcnt vmcnt(4)" ::: "memory");
        __builtin_amdgcn_s_barrier();
        __builtin_amdgcn_sched_barrier(0);
    }

#pragma unroll
    for (int m = 0; m < 4; ++m)
#pragma unroll
        for (int n = 0; n < 4; ++n) {
            int row0 = m0 + wm * 64 + m * 16 + g * 4;
            int col  = n0 + wn * 64 + n * 16 + lr;
#pragma unroll
            for (int r = 0; r < 4; ++r) {
                float v = acc[m][n][r];
                if (OUT_BF16)
                    Cb[(size_t)(row0 + r) * N + col] = f2b(v);
                else
                    Cf[(size_t)(row0 + r) * N + col] = v + bias[col];
            }
        }
}

// ---------------- V transpose: Cqkv V-part [s][d] -> Vt[b][h][d][s] bf16 ----------------
__global__ __launch_bounds__(256) void vt_kernel(const ushort_t* __restrict__ Cqkv,
                                                 ushort_t* __restrict__ Vt) {
    int b = blockIdx.z, h = blockIdx.y, st = blockIdx.x;
    __shared__ ushort_t t[64][72];
    const ushort_t* src = Cqkv + (size_t)b * 2048 * 3072 + 2048 + (size_t)h * 64;
    int tid = threadIdx.x;
#pragma unroll
    for (int i = 0; i < 2; ++i) {
        int c = tid + i * 256;
        int sl = c >> 3, dc = (c & 7) * 8;
        *(bf16x8*)&t[sl][dc] = *(const bf16x8*)(src + (size_t)(st * 64 + sl) * 3072 + dc);
    }
    __syncthreads();
#pragma unroll
    for (int i = 0; i < 2; ++i) {
        int c = tid + i * 256;
        int d = c >> 3, sc = (c & 7) * 8;
        bf16x8 v;
#pragma unroll
        for (int j = 0; j < 8; ++j) v[j] = (short)t[sc + j][d];
        *(bf16x8*)(Vt + ((size_t)(b * 16 + h) * 64 + d) * 2048 + st * 64 + sc) = v;
    }
}

// ---------------- attn kernel A: softmax denominators + ALL zero-fill ----------------
// Latency-paced compute kernel: its idle store pipe absorbs the 520 MB of
// strictly-upper P zero tiles (4 tiles per round at round top -> free drain).
__global__ __launch_bounds__(256, 5) void attn_sums_kernel(const ushort_t* __restrict__ Cqkv,
                                                           float* __restrict__ lnlbuf,
                                                           float* __restrict__ Pout) {
    const int S = 2048, DQ = 3072;
    const float C1 = 0.18033688f;
    const float C2 = 5.77078016f;

    int z = (int)blockIdx.x;
    int c = z & 255, j = z >> 8;
    int p = P4tab[(c & 3) * 4 + j];
    int h = (c >> 2) & 15, b = c >> 6;
    int qtA = p, qtB = 31 - p;        // qtB >= 16

    int tid = threadIdx.x, wid = tid >> 6, lane = tid & 63;
    int g = lane >> 4, lr = lane & 15;
    int vsr = tid >> 2, vsc = (tid & 3) * 16;

    __shared__ ushort_t KV[4][4096];   // 2 super-slots of 16KB

    const ushort_t* Qb = Cqkv + (size_t)b * S * DQ + (size_t)h * 64;
    const ushort_t* Kb = Cqkv + (size_t)b * S * DQ + 1024 + (size_t)h * 64;
    float* PbaseA = Pout + (((size_t)(b * 16 + h)) * S + qtA * 64) * S;
    float* PbaseB = Pout + (((size_t)(b * 16 + h)) * S + qtB * 64) * S;

    int srow = lane >> 3;
    int scol = ((lane & 7) ^ srow) * 8;

    int zcnt = 0;   // 31 zero tiles total per block
    auto zfill = [&](int zi) {
        float* base; int tt;
        if (zi < 31 - qtA) { base = PbaseA; tt = qtA + 1 + zi; }
        else               { base = PbaseB; tt = qtB + 1 + (zi - (31 - qtA)); }
        float* dst = base + (size_t)vsr * S + tt * 64 + vsc;
        f32x4 zf = {0.f, 0.f, 0.f, 0.f};
#pragma unroll
        for (int jj = 0; jj < 4; ++jj) ((f32x4*)dst)[jj] = zf;
    };

    auto stageK2 = [&](int ss, int t0, int t1) {
        char* dst = (char*)&KV[ss * 2][0] + wid * 1024;
        gload_lds16(Kb + (size_t)(t0 * 64 + wid * 8 + srow) * DQ + scol, dst);
        gload_lds16(Kb + (size_t)(t0 * 64 + 32 + wid * 8 + srow) * DQ + scol, dst + 4096);
        gload_lds16(Kb + (size_t)(t1 * 64 + wid * 8 + srow) * DQ + scol, dst + 8192);
        gload_lds16(Kb + (size_t)(t1 * 64 + 32 + wid * 8 + srow) * DQ + scol, dst + 12288);
    };

    bf16x8 qfA[2], qfB[2];
    {
        const ushort_t* qa = Qb + (size_t)(qtA * 64 + wid * 16 + lr) * DQ + g * 8;
        qfA[0] = *(const bf16x8*)qa;
        qfA[1] = *(const bf16x8*)(qa + 32);
        const ushort_t* qb2 = Qb + (size_t)(qtB * 64 + wid * 16 + lr) * DQ + g * 8;
        qfB[0] = *(const bf16x8*)qb2;
        qfB[1] = *(const bf16x8*)(qb2 + 32);
    }
    int qloc = wid * 16 + lr;

    float psA = 0.f, psB = 0.f;

    auto p1_tile = [&](const char* ksb, int tt) {
#pragma unroll
        for (int nb = 0; nb < 4; ++nb) {
            int row = nb * 16 + lr;
            int x = (row & 7) << 4;
            bf16x8 k0 = *(const bf16x8*)(ksb + row * 128 + ((g * 16) ^ x));
            bf16x8 k1 = *(const bf16x8*)(ksb + row * 128 + ((64 + g * 16) ^ x));
            f32x4 sB = {};
            sB = __builtin_amdgcn_mfma_f32_16x16x32_bf16(k0, qfB[0], sB, 0, 0, 0);
            sB = __builtin_amdgcn_mfma_f32_16x16x32_bf16(k1, qfB[1], sB, 0, 0, 0);
            if (tt == qtB) {
#pragma unroll
                for (int r = 0; r < 4; ++r)
                    if (nb * 16 + g * 4 + r <= qloc) psB += exp2f(fmaf(sB[r], C1, -C2));
            } else {
#pragma unroll
                for (int r = 0; r < 4; ++r) psB += exp2f(fmaf(sB[r], C1, -C2));
            }
            if (tt <= qtA) {
                f32x4 sA = {};
                sA = __builtin_amdgcn_mfma_f32_16x16x32_bf16(k0, qfA[0], sA, 0, 0, 0);
                sA = __builtin_amdgcn_mfma_f32_16x16x32_bf16(k1, qfA[1], sA, 0, 0, 0);
                if (tt == qtA) {
#pragma unroll
                    for (int r = 0; r < 4; ++r)
                        if (nb * 16 + g * 4 + r <= qloc) psA += exp2f(fmaf(sA[r], C1, -C2));
                } else {
#pragma unroll
                    for (int r = 0; r < 4; ++r) psA += exp2f(fmaf(sA[r], C1, -C2));
                }
            }
        }
    };

    int nR = (qtB + 2) >> 1;   // in [9,16]; 4 zfill/round * 9 >= 31 always covers
    stageK2(0, 0, 1);
    asm volatile("s_waitcnt vmcnt(0)" ::: "memory");
    __builtin_amdgcn_s_barrier();
    __builtin_amdgcn_sched_barrier(0);
    for (int ri = 0; ri < nR; ++ri) {
#pragma unroll
        for (int k = 0; k < 4; ++k)
            if (zcnt < 31) zfill(zcnt++);
        int t0n = 2 * ri + 2, t1n = 2 * ri + 3;
        if (t0n > qtB) t0n = qtB;
        if (t1n > qtB) t1n = qtB;
        stageK2((ri + 1) & 1, t0n, t1n);
        const char* ksb = (const char*)&KV[(ri & 1) * 2][0];
        __builtin_amdgcn_s_setprio(1);
        p1_tile(ksb, 2 * ri);
        if (2 * ri + 1 <= qtB) p1_tile(ksb + 8192, 2 * ri + 1);
        __builtin_amdgcn_s_setprio(0);
        asm volatile("s_waitcnt vmcnt(0)" ::: "memory");
        __builtin_amdgcn_s_barrier();
        __builtin_amdgcn_sched_barrier(0);
    }
    psA += __shfl_xor(psA, 16); psA += __shfl_xor(psA, 32);
    psB += __shfl_xor(psB, 16); psB += __shfl_xor(psB, 32);
    if (g == 0) {
        float* dst = lnlbuf + (size_t)(b * 16 + h) * S;
        dst[qtA * 64 + qloc] = __log2f(psA) + C2;
        dst[qtB * 64 + qloc] = __log2f(psB) + C2;
    }
}

// ---------------- attn kernel B: P + PV only (no zero-fill) ----------------
// Store-paced end-to-end; every byte it stores is wall time, so it stores
// ONLY live P. Counted vmcnt lets the 8 newest P stores linger across barriers.
__global__ __launch_bounds__(256, 4) void attn_pv_kernel(const ushort_t* __restrict__ Cqkv,
                                                         const ushort_t* __restrict__ Vtg,
                                                         const float* __restrict__ lnlbuf,
                                                         float* __restrict__ Pout,
                                                         ushort_t* __restrict__ Oout) {
    const int S = 2048, DQ = 3072;
    const float C1 = 0.18033688f;

    int z = (int)blockIdx.x;
    int c = z & 255, j = z >> 8;
    int p = P4tab[(c & 3) * 4 + j];
    int h = (c >> 2) & 15, b = c >> 6;
    int qtA = p, qtB = 31 - p;

    int tid = threadIdx.x, wid = tid >> 6, lane = tid & 63;
    int g = lane >> 4, lr = lane & 15;

    __shared__ ushort_t KV[4][4096];   // K dbuf {0,1}, V dbuf {2,3}
    __shared__ ushort_t Pl[4096];
    char* PlB = (char*)Pl + wid * 2048;

    const ushort_t* Qb = Cqkv + (size_t)b * S * DQ + (size_t)h * 64;
    const ushort_t* Kb = Cqkv + (size_t)b * S * DQ + 1024 + (size_t)h * 64;
    const ushort_t* Vb = Vtg + (size_t)((b * 16 + h) * 64) * 2048;
    float* PbaseA = Pout + (((size_t)(b * 16 + h)) * S + qtA * 64) * S;
    float* PbaseB = Pout + (((size_t)(b * 16 + h)) * S + qtB * 64) * S;

    int srow = lane >> 3;
    int scol = ((lane & 7) ^ srow) * 8;

    auto stageK = [&](int ri, int tt) {
        char* dst = (char*)&KV[ri][0] + wid * 1024;
        gload_lds16(Kb + (size_t)(tt * 64 + wid * 8 + srow) * DQ + scol, dst);
        gload_lds16(Kb + (size_t)(tt * 64 + 32 + wid * 8 + srow) * DQ + scol, dst + 4096);
    };
    auto stageV = [&](int ri, int tt) {
        char* dst = (char*)&KV[2 + ri][0] + wid * 1024;
        gload_lds16(Vb + (size_t)(wid * 8 + srow) * 2048 + tt * 64 + scol, dst);
        gload_lds16(Vb + (size_t)(32 + wid * 8 + srow) * 2048 + tt * 64 + scol, dst + 4096);
    };

    bf16x8 qfA[2], qfB[2];
    {
        const ushort_t* qa = Qb + (size_t)(qtA * 64 + wid * 16 + lr) * DQ + g * 8;
        qfA[0] = *(const bf16x8*)qa;
        qfA[1] = *(const bf16x8*)(qa + 32);
        const ushort_t* qb2 = Qb + (size_t)(qtB * 64 + wid * 16 + lr) * DQ + g * 8;
        qfB[0] = *(const bf16x8*)qb2;
        qfB[1] = *(const bf16x8*)(qb2 + 32);
    }
    int qloc = wid * 16 + lr;

    float lnA = lnlbuf[(size_t)(b * 16 + h) * S + qtA * 64 + qloc];
    float lnB = lnlbuf[(size_t)(b * 16 + h) * S + qtB * 64 + qloc];

    f32x4 OA[4] = {}, OB[4] = {};
    stageK(0, 0);
    stageV(0, 0);
    __syncthreads();
    int buf = 0;
    for (int tt = 0; tt <= qtB; ++tt) {
        if (tt < qtB) { stageK(buf ^ 1, tt + 1); stageV(buf ^ 1, tt + 1); }
        const char* ksb = (const char*)&KV[buf][0];
        const char* vsb = (const char*)&KV[2 + buf][0];

        // ----- tile B -----
        {
            f32x4 pv[4];
            __builtin_amdgcn_s_setprio(1);
#pragma unroll
            for (int nb = 0; nb < 4; ++nb) {
                int row = nb * 16 + lr;
                int x = (row & 7) << 4;
                f32x4 s = {};
                s = __builtin_amdgcn_mfma_f32_16x16x32_bf16(*(const bf16x8*)(ksb + row * 128 + ((g * 16) ^ x)), qfB[0], s, 0, 0, 0);
                s = __builtin_amdgcn_mfma_f32_16x16x32_bf16(*(const bf16x8*)(ksb + row * 128 + ((64 + g * 16) ^ x)), qfB[1], s, 0, 0, 0);
#pragma unroll
                for (int r = 0; r < 4; ++r) {
                    float v = exp2f(fmaf(s[r], C1, -lnB));
                    if (tt == qtB && (nb * 16 + g * 4 + r > qloc)) v = 0.f;
                    pv[nb][r] = v;
                }
            }
            __builtin_amdgcn_s_setprio(0);
#pragma unroll
            for (int nb = 0; nb < 4; ++nb)
                *(f32x4*)(PbaseB + (size_t)qloc * S + tt * 64 + nb * 16 + g * 4) = pv[nb];
#pragma unroll
            for (int nb = 0; nb < 4; ++nb) {
                uint_t w0, w1;
                asm("v_cvt_pk_bf16_f32 %0, %1, %2" : "=v"(w0) : "v"(pv[nb][0]), "v"(pv[nb][1]));
                asm("v_cvt_pk_bf16_f32 %0, %1, %2" : "=v"(w1) : "v"(pv[nb][2]), "v"(pv[nb][3]));
                uint2 w; w.x = w0; w.y = w1;
                *(uint2*)(PlB + ((lr * 128 + nb * 32 + g * 8) ^ ((lr & 7) << 4))) = w;
            }
            __builtin_amdgcn_wave_barrier();
            __builtin_amdgcn_s_setprio(1);
#pragma unroll
            for (int kc = 0; kc < 2; ++kc) {
                bf16x8 pf = *(const bf16x8*)(PlB + ((lr * 128 + kc * 64 + g * 16) ^ ((lr & 7) << 4)));
#pragma unroll
                for (int nb = 0; nb < 4; ++nb) {
                    int vrow = nb * 16 + lr;
                    bf16x8 vf = *(const bf16x8*)(vsb + vrow * 128 + ((kc * 64 + g * 16) ^ ((vrow & 7) << 4)));
                    OB[nb] = __builtin_amdgcn_mfma_f32_16x16x32_bf16(pf, vf, OB[nb], 0, 0, 0);
                }
            }
            __builtin_amdgcn_s_setprio(0);
            __builtin_amdgcn_wave_barrier();
        }

        // ----- tile A (subset range) -----
        if (tt <= qtA) {
            f32x4 pv[4];
            __builtin_amdgcn_s_setprio(1);
#pragma unroll
            for (int nb = 0; nb < 4; ++nb) {
                int row = nb * 16 + lr;
                int x = (row & 7) << 4;
                f32x4 s = {};
                s = __builtin_amdgcn_mfma_f32_16x16x32_bf16(*(const bf16x8*)(ksb + row * 128 + ((g * 16) ^ x)), qfA[0], s, 0, 0, 0);
                s = __builtin_amdgcn_mfma_f32_16x16x32_bf16(*(const bf16x8*)(ksb + row * 128 + ((64 + g * 16) ^ x)), qfA[1], s, 0, 0, 0);
#pragma unroll
                for (int r = 0; r < 4; ++r) {
                    float v = exp2f(fmaf(s[r], C1, -lnA));
                    if (tt == qtA && (nb * 16 + g * 4 + r > qloc)) v = 0.f;
                    pv[nb][r] = v;
                }
            }
            __builtin_amdgcn_s_setprio(0);
#pragma unroll
            for (int nb = 0; nb < 4; ++nb)
                *(f32x4*)(PbaseA + (size_t)qloc * S + tt * 64 + nb * 16 + g * 4) = pv[nb];
#pragma unroll
            for (int nb = 0; nb < 4; ++nb) {
                uint_t w0, w1;
                asm("v_cvt_pk_bf16_f32 %0, %1, %2" : "=v"(w0) : "v"(pv[nb][0]), "v"(pv[nb][1]));
                asm("v_cvt_pk_bf16_f32 %0, %1, %2" : "=v"(w1) : "v"(pv[nb][2]), "v"(pv[nb][3]));
                uint2 w; w.x = w0; w.y = w1;
                *(uint2*)(PlB + ((lr * 128 + nb * 32 + g * 8) ^ ((lr & 7) << 4))) = w;
            }
            __builtin_amdgcn_wave_barrier();
            __builtin_amdgcn_s_setprio(1);
#pragma unroll
            for (int kc = 0; kc < 2; ++kc) {
                bf16x8 pf = *(const bf16x8*)(PlB + ((lr * 128 + kc * 64 + g * 16) ^ ((lr & 7) << 4)));
#pragma unroll
                for (int nb = 0; nb < 4; ++nb) {
                    int vrow = nb * 16 + lr;
                    bf16x8 vf = *(const bf16x8*)(vsb + vrow * 128 + ((kc * 64 + g * 16) ^ ((vrow & 7) << 4)));
                    OA[nb] = __builtin_amdgcn_mfma_f32_16x16x32_bf16(pf, vf, OA[nb], 0, 0, 0);
                }
            }
            __builtin_amdgcn_s_setprio(0);
            __builtin_amdgcn_wave_barrier();
            asm volatile("s_waitcnt vmcnt(8)" ::: "memory");
        } else {
            asm volatile("s_waitcnt vmcnt(4)" ::: "memory");
        }
        __builtin_amdgcn_s_barrier();
        __builtin_amdgcn_sched_barrier(0);
        buf ^= 1;
    }

    // write O (bf16) as [B,S,H*Dh] for both tiles
#pragma unroll
    for (int nb = 0; nb < 4; ++nb)
#pragma unroll
        for (int r = 0; r < 4; ++r) {
            int qA = qtA * 64 + wid * 16 + g * 4 + r;
            int qB = qtB * 64 + wid * 16 + g * 4 + r;
            Oout[((size_t)b * S + qA) * 1024 + h * 64 + nb * 16 + lr] = f2b(OA[nb][r]);
            Oout[((size_t)b * S + qB) * 1024 + h * 64 + nb * 16 + lr] = f2b(OB[nb][r]);
        }
}

extern "C" void kernel_launch(void* const* d_in, const int* in_sizes, int n_in,
                              void* d_out, int out_size, void* d_ws, size_t ws_size,
                              hipStream_t stream) {
    const float* x  = (const float*)d_in[0];
    const float* Wq = (const float*)d_in[1];
    const float* Wk = (const float*)d_in[2];
    const float* Wv = (const float*)d_in[3];
    const float* Wo = (const float*)d_in[4];
    const float* bo = (const float*)d_in[5];

    float* out  = (float*)d_out;
    float* Pout = out + (size_t)8388608; // attn_probs region

    char* ws = (char*)d_ws;
    ushort_t* xb    = (ushort_t*)(ws);                       // 16 MB
    ushort_t* wqkv  = (ushort_t*)(ws + (16u << 20));         // 6 MB [3072][1024]
    ushort_t* wob   = (ushort_t*)(ws + (22u << 20));         // 2 MB
    ushort_t* Cqkv  = (ushort_t*)(ws + (24u << 20));         // 48 MB [8192][3072]
    ushort_t* Vtw   = (ushort_t*)(ws + (72u << 20));         // 32 MB [b*16+h][64][2048]
    ushort_t* attnb = (ushort_t*)(ws + (104u << 20));        // 16 MB
    float*    lnl   = (float*)(ws + (120u << 20));           // 512 KB [b*16+h][2048]

    // 1. dtype conversions / weight transposes
    convert_x_kernel<<<8192, 256, 0, stream>>>(x, xb, 2097152);
    transpose_w4_kernel<<<dim3(32, 32, 4), dim3(32, 8), 0, stream>>>(Wq, Wk, Wv, Wo, wqkv, wob);

    // 2. fused QKV projection: Cqkv[8192][3072]
    gemm_kernel<3072, 1><<<dim3(64, 24), 256, 0, stream>>>(xb, wqkv, Cqkv, nullptr, nullptr);

    // 3. V transpose to [b][h][d][s]
    vt_kernel<<<dim3(32, 16, 4), 256, 0, stream>>>(Cqkv, Vtw);

    // 4a. softmax denominators + all P zero-fill (stores ride the latency slots)
    attn_sums_kernel<<<1024, 256, 0, stream>>>(Cqkv, lnl, Pout);

    // 4b. P + PV only (store-paced: stores only live bytes)
    attn_pv_kernel<<<1024, 256, 0, stream>>>(Cqkv, Vtw, lnl, Pout, attnb);

    // 5. output projection + bias (fp32 out)
    gemm_kernel<1024, 0><<<dim3(64, 8), 256, 0, stream>>>(attnb, wob, nullptr, out, bo);
}

// Round 16
// 474.048 us; speedup vs baseline: 1.0651x; 1.0651x over previous
//
#include <hip/hip_runtime.h>
#include <hip/hip_bf16.h>

typedef __attribute__((ext_vector_type(8))) short bf16x8;
typedef __attribute__((ext_vector_type(4))) float f32x4;
typedef unsigned short ushort_t;
typedef unsigned int uint_t;

#define AS1 __attribute__((address_space(1)))
#define AS3 __attribute__((address_space(3)))

__constant__ int P4tab[16] = {0, 5, 10, 15, 1, 4, 11, 14, 2, 7, 8, 13, 3, 6, 9, 12};

__device__ __forceinline__ void gload_lds16(const void* g, void* l) {
    __builtin_amdgcn_global_load_lds((const AS1 void*)g, (AS3 void*)l, 16, 0, 0);
}

__device__ __forceinline__ ushort_t f2b(float f) {
    unsigned u = __builtin_bit_cast(unsigned, f);
    unsigned r = (u + 0x7FFFu + ((u >> 16) & 1u)) >> 16;
    return (ushort_t)r;
}

// ---------------- convert x (fp32 -> bf16) ----------------
__global__ __launch_bounds__(256) void convert_x_kernel(const float* __restrict__ in,
                                                        ushort_t* __restrict__ out, int n4) {
    int i = blockIdx.x * blockDim.x + threadIdx.x;
    if (i < n4) {
        float4 f = ((const float4*)in)[i];
        ushort4 u;
        u.x = f2b(f.x); u.y = f2b(f.y); u.z = f2b(f.z); u.w = f2b(f.w);
        ((ushort4*)out)[i] = u;
    }
}

// ---------------- transpose+convert ALL weights in one launch ----------------
__global__ __launch_bounds__(256) void transpose_w4_kernel(const float* __restrict__ W0,
                                                           const float* __restrict__ W1,
                                                           const float* __restrict__ W2,
                                                           const float* __restrict__ W3,
                                                           ushort_t* __restrict__ WTqkv,
                                                           ushort_t* __restrict__ WTo) {
    __shared__ float t[32][33];
    int which = blockIdx.z;
    const float* W = (which == 0) ? W0 : (which == 1) ? W1 : (which == 2) ? W2 : W3;
    ushort_t* WT = (which < 3) ? (WTqkv + (size_t)which * 1024 * 1024) : WTo;
    int n0 = blockIdx.x * 32, k0 = blockIdx.y * 32;
    int tx = threadIdx.x, ty = threadIdx.y; // block (32,8)
    for (int i = 0; i < 4; ++i)
        t[ty + i * 8][tx] = W[(size_t)(k0 + ty + i * 8) * 1024 + n0 + tx];
    __syncthreads();
    for (int i = 0; i < 4; ++i)
        WT[(size_t)(n0 + ty + i * 8) * 1024 + k0 + tx] = f2b(t[tx][ty + i * 8]);
}

// ---------------- bf16 MFMA GEMM: 3-slot ring, 2-deep prefetch, counted vmcnt ----------------
template <int N, int OUT_BF16>
__global__ __launch_bounds__(256) void gemm_kernel(const ushort_t* __restrict__ A,
                                                   const ushort_t* __restrict__ BT,
                                                   ushort_t* __restrict__ Cb,
                                                   float* __restrict__ Cf,
                                                   const float* __restrict__ bias) {
    const int K = 1024;
    __shared__ ushort_t As[3 * 128 * 32];
    __shared__ ushort_t Bs[3 * 128 * 32];
    int tid = threadIdx.x;
    int wid = tid >> 6, lane = tid & 63;
    int g = lane >> 4, lr = lane & 15;

    // bijective XCD swizzle (nwg % 8 == 0 for both grids)
    int zz = (int)blockIdx.x + 64 * (int)blockIdx.y;
    int nwg = 64 * (int)gridDim.y;
    int zs = (zz & 7) * (nwg >> 3) + (zz >> 3);
    int m0 = (zs % 64) * 128, n0 = (zs / 64) * 128;

    int wm = wid >> 1, wn = wid & 1;

    f32x4 acc[4][4] = {};

    int c0 = wid * 2;
    int lrow = lane >> 2;
    int lcol = ((lane & 3) ^ ((lane >> 3) & 3)) * 8;
    const ushort_t* Ag0 = A  + (size_t)(m0 + c0 * 16 + lrow) * K + lcol;
    const ushort_t* Ag1 = A  + (size_t)(m0 + c0 * 16 + 16 + lrow) * K + lcol;
    const ushort_t* Bg0 = BT + (size_t)(n0 + c0 * 16 + lrow) * K + lcol;
    const ushort_t* Bg1 = BT + (size_t)(n0 + c0 * 16 + 16 + lrow) * K + lcol;

    int swzA = ((lr >> 1) & 3) << 4;

    auto stage = [&](int si, int kt) {
        char* a0 = (char*)As + si * 8192 + c0 * 1024;
        char* b0 = (char*)Bs + si * 8192 + c0 * 1024;
        gload_lds16(Ag0 + kt * 32, a0);
        gload_lds16(Ag1 + kt * 32, a0 + 1024);
        gload_lds16(Bg0 + kt * 32, b0);
        gload_lds16(Bg1 + kt * 32, b0 + 1024);
    };

    stage(0, 0);
    stage(1, 1);
    asm volatile("s_waitcnt vmcnt(4)" ::: "memory");
    __builtin_amdgcn_s_barrier();
    __builtin_amdgcn_sched_barrier(0);
    for (int kt = 0; kt < 32; ++kt) {
        int nt = kt + 2;
        stage(nt % 3, nt < 32 ? nt : 31);   // dummy re-stage at tail keeps count uniform
        const char* ab = (const char*)As + (kt % 3) * 8192;
        const char* bb = (const char*)Bs + (kt % 3) * 8192;
        bf16x8 af[4], bfr[4];
#pragma unroll
        for (int m = 0; m < 4; ++m) {
            int row = wm * 64 + m * 16 + lr;
            af[m] = *(const bf16x8*)(ab + row * 64 + ((g * 16) ^ swzA));
        }
#pragma unroll
        for (int n = 0; n < 4; ++n) {
            int row = wn * 64 + n * 16 + lr;
            bfr[n] = *(const bf16x8*)(bb + row * 64 + ((g * 16) ^ swzA));
        }
#pragma unroll
        for (int m = 0; m < 4; ++m)
#pragma unroll
            for (int n = 0; n < 4; ++n)
                acc[m][n] = __builtin_amdgcn_mfma_f32_16x16x32_bf16(af[m], bfr[n], acc[m][n], 0, 0, 0);
        // wait all but the newest 4 loads (the kt+2 prefetch): tile kt+1 ready
        asm volatile("s_waitcnt vmcnt(4)" ::: "memory");
        __builtin_amdgcn_s_barrier();
        __builtin_amdgcn_sched_barrier(0);
    }

#pragma unroll
    for (int m = 0; m < 4; ++m)
#pragma unroll
        for (int n = 0; n < 4; ++n) {
            int row0 = m0 + wm * 64 + m * 16 + g * 4;
            int col  = n0 + wn * 64 + n * 16 + lr;
#pragma unroll
            for (int r = 0; r < 4; ++r) {
                float v = acc[m][n][r];
                if (OUT_BF16)
                    Cb[(size_t)(row0 + r) * N + col] = f2b(v);
                else
                    Cf[(size_t)(row0 + r) * N + col] = v + bias[col];
            }
        }
}

// ---------------- V transpose: Cqkv V-part [s][d] -> Vt[b][h][d][s] bf16 ----------------
__global__ __launch_bounds__(256) void vt_kernel(const ushort_t* __restrict__ Cqkv,
                                                 ushort_t* __restrict__ Vt) {
    int b = blockIdx.z, h = blockIdx.y, st = blockIdx.x;
    __shared__ ushort_t t[64][72];
    const ushort_t* src = Cqkv + (size_t)b * 2048 * 3072 + 2048 + (size_t)h * 64;
    int tid = threadIdx.x;
#pragma unroll
    for (int i = 0; i < 2; ++i) {
        int c = tid + i * 256;
        int sl = c >> 3, dc = (c & 7) * 8;
        *(bf16x8*)&t[sl][dc] = *(const bf16x8*)(src + (size_t)(st * 64 + sl) * 3072 + dc);
    }
    __syncthreads();
#pragma unroll
    for (int i = 0; i < 2; ++i) {
        int c = tid + i * 256;
        int d = c >> 3, sc = (c & 7) * 8;
        bf16x8 v;
#pragma unroll
        for (int j = 0; j < 8; ++j) v[j] = (short)t[sc + j][d];
        *(bf16x8*)(Vt + ((size_t)(b * 16 + h) * 64 + d) * 2048 + st * 64 + sc) = v;
    }
}

// ---------------- fused attention: paired q-tiles, zero-fill interleaved (R11 best) ----------------
// The 31 zero tiles per block are streamed at the TOP of barrier rounds (pass 1:
// 1/round, pass 2: 2/round clamped) — stores issued at round top have a full
// round to commit, so the round-end vmcnt drain of them is free.
__global__ __launch_bounds__(256, 4) void attn_kernel(const ushort_t* __restrict__ Cqkv,
                                                      const ushort_t* __restrict__ Vtg,
                                                      float* __restrict__ Pout,
                                                      ushort_t* __restrict__ Oout) {
    const int S = 2048, DQ = 3072;
    const float C1 = 0.18033688f;   // 0.125 * log2(e)
    const float C2 = 5.77078016f;   // 4 * log2(e)

    int z = (int)blockIdx.x;
    int c = z & 255, j = z >> 8;
    int p = P4tab[(c & 3) * 4 + j];   // equal-sum pairing per CU
    int h = (c >> 2) & 15, b = c >> 6;
    int qtA = p, qtB = 31 - p;        // qtB >= 16

    int tid = threadIdx.x, wid = tid >> 6, lane = tid & 63;
    int g = lane >> 4, lr = lane & 15;
    int vsr = tid >> 2, vsc = (tid & 3) * 16;

    __shared__ ushort_t KV[4][4096];   // pass1: 2 super-slots of 16KB; pass2: K dbuf {0,1}, V dbuf {2,3}
    __shared__ ushort_t Pl[4096];      // 4 waves x [16 q][64 t] bf16 (A/B sequential)
    char* PlB = (char*)Pl + wid * 2048;

    const ushort_t* Qb = Cqkv + (size_t)b * S * DQ + (size_t)h * 64;
    const ushort_t* Kb = Cqkv + (size_t)b * S * DQ + 1024 + (size_t)h * 64;
    const ushort_t* Vb = Vtg + (size_t)((b * 16 + h) * 64) * 2048;
    float* PbaseA = Pout + (((size_t)(b * 16 + h)) * S + qtA * 64) * S;
    float* PbaseB = Pout + (((size_t)(b * 16 + h)) * S + qtB * 64) * S;

    int srow = lane >> 3;
    int scol = ((lane & 7) ^ srow) * 8;   // pre-swizzled source chunk

    // zero-fill one 64x64 tile of the strictly-upper region; zi in [0, 31)
    auto zfill = [&](int zi) {
        float* base; int tt;
        if (zi < 31 - qtA) { base = PbaseA; tt = qtA + 1 + zi; }
        else               { base = PbaseB; tt = qtB + 1 + (zi - (31 - qtA)); }
        float* dst = base + (size_t)vsr * S + tt * 64 + vsc;
        f32x4 zf = {0.f, 0.f, 0.f, 0.f};
#pragma unroll
        for (int jj = 0; jj < 4; ++jj) ((f32x4*)dst)[jj] = zf;
    };

    auto stageK = [&](int ri, int tt) {
        char* dst = (char*)&KV[ri][0] + wid * 1024;
        gload_lds16(Kb + (size_t)(tt * 64 + wid * 8 + srow) * DQ + scol, dst);
        gload_lds16(Kb + (size_t)(tt * 64 + 32 + wid * 8 + srow) * DQ + scol, dst + 4096);
    };
    auto stageV = [&](int ri, int tt) {
        char* dst = (char*)&KV[2 + ri][0] + wid * 1024;
        gload_lds16(Vb + (size_t)(wid * 8 + srow) * 2048 + tt * 64 + scol, dst);
        gload_lds16(Vb + (size_t)(32 + wid * 8 + srow) * 2048 + tt * 64 + scol, dst + 4096);
    };
    // stage TWO K tiles (16 KB) into super-slot ss in {0,1}
    auto stageK2 = [&](int ss, int t0, int t1) {
        char* dst = (char*)&KV[ss * 2][0] + wid * 1024;
        gload_lds16(Kb + (size_t)(t0 * 64 + wid * 8 + srow) * DQ + scol, dst);
        gload_lds16(Kb + (size_t)(t0 * 64 + 32 + wid * 8 + srow) * DQ + scol, dst + 4096);
        gload_lds16(Kb + (size_t)(t1 * 64 + wid * 8 + srow) * DQ + scol, dst + 8192);
        gload_lds16(Kb + (size_t)(t1 * 64 + 32 + wid * 8 + srow) * DQ + scol, dst + 12288);
    };

    // Q fragments for both tiles (B-operand: col=lr -> q row)
    bf16x8 qfA[2], qfB[2];
    {
        const ushort_t* qa = Qb + (size_t)(qtA * 64 + wid * 16 + lr) * DQ + g * 8;
        qfA[0] = *(const bf16x8*)qa;
        qfA[1] = *(const bf16x8*)(qa + 32);
        const ushort_t* qb2 = Qb + (size_t)(qtB * 64 + wid * 16 + lr) * DQ + g * 8;
        qfB[0] = *(const bf16x8*)qb2;
        qfB[1] = *(const bf16x8*)(qb2 + 32);
    }
    int qloc = wid * 16 + lr;   // this lane's q row (local 0..63)

    // ---- pass 1 (merged, double-tile rounds): per-lane sums of exp2(s*C1 - C2) ----
    float psA = 0.f, psB = 0.f;

    auto p1_tile = [&](const char* ksb, int tt) {
#pragma unroll
        for (int nb = 0; nb < 4; ++nb) {
            int row = nb * 16 + lr;
            int x = (row & 7) << 4;
            bf16x8 k0 = *(const bf16x8*)(ksb + row * 128 + ((g * 16) ^ x));
            bf16x8 k1 = *(const bf16x8*)(ksb + row * 128 + ((64 + g * 16) ^ x));
            f32x4 sB = {};
            sB = __builtin_amdgcn_mfma_f32_16x16x32_bf16(k0, qfB[0], sB, 0, 0, 0);
            sB = __builtin_amdgcn_mfma_f32_16x16x32_bf16(k1, qfB[1], sB, 0, 0, 0);
            if (tt == qtB) {
#pragma unroll
                for (int r = 0; r < 4; ++r)
                    if (nb * 16 + g * 4 + r <= qloc) psB += exp2f(fmaf(sB[r], C1, -C2));
            } else {
#pragma unroll
                for (int r = 0; r < 4; ++r) psB += exp2f(fmaf(sB[r], C1, -C2));
            }
            if (tt <= qtA) {
                f32x4 sA = {};
                sA = __builtin_amdgcn_mfma_f32_16x16x32_bf16(k0, qfA[0], sA, 0, 0, 0);
                sA = __builtin_amdgcn_mfma_f32_16x16x32_bf16(k1, qfA[1], sA, 0, 0, 0);
                if (tt == qtA) {
#pragma unroll
                    for (int r = 0; r < 4; ++r)
                        if (nb * 16 + g * 4 + r <= qloc) psA += exp2f(fmaf(sA[r], C1, -C2));
                } else {
#pragma unroll
                    for (int r = 0; r < 4; ++r) psA += exp2f(fmaf(sA[r], C1, -C2));
                }
            }
        }
    };

    int nR = (qtB + 2) >> 1;   // rounds; round ri covers tiles 2ri, 2ri+1. nR in [9,16]
    stageK2(0, 0, 1);          // qtB >= 16
    asm volatile("s_waitcnt vmcnt(0)" ::: "memory");
    __builtin_amdgcn_s_barrier();
    __builtin_amdgcn_sched_barrier(0);
    for (int ri = 0; ri < nR; ++ri) {
        zfill(ri);                         // zero tile zi=ri (drain-free: full round to commit)
        int t0n = 2 * ri + 2, t1n = 2 * ri + 3;
        if (t0n > qtB) t0n = qtB;          // dummy re-stage at tail
        if (t1n > qtB) t1n = qtB;
        stageK2((ri + 1) & 1, t0n, t1n);
        const char* ksb = (const char*)&KV[(ri & 1) * 2][0];
        __builtin_amdgcn_s_setprio(1);
        p1_tile(ksb, 2 * ri);
        if (2 * ri + 1 <= qtB) p1_tile(ksb + 8192, 2 * ri + 1);
        __builtin_amdgcn_s_setprio(0);
        asm volatile("s_waitcnt vmcnt(0)" ::: "memory");
        __builtin_amdgcn_s_barrier();
        __builtin_amdgcn_sched_barrier(0);
    }
    psA += __shfl_xor(psA, 16); psA += __shfl_xor(psA, 32);
    psB += __shfl_xor(psB, 16); psB += __shfl_xor(psB, 32);
    float lnA = __log2f(psA) + C2;
    float lnB = __log2f(psB) + C2;

    // ---- pass 2 (merged): P + PV for B always, A when tt<=qtA ----
    f32x4 OA[4] = {}, OB[4] = {};
    stageK(0, 0);
    stageV(0, 0);
    __syncthreads();
    int buf = 0;
    for (int tt = 0; tt <= qtB; ++tt) {
        // remaining zero tiles, 2 per round clamped (issued at round top: drain-free)
        {
            int z0 = nR + 2 * tt;
            if (z0 < 31) { zfill(z0); if (z0 + 1 < 31) zfill(z0 + 1); }
        }
        if (tt < qtB) { stageK(buf ^ 1, tt + 1); stageV(buf ^ 1, tt + 1); }
        const char* ksb = (const char*)&KV[buf][0];
        const char* vsb = (const char*)&KV[2 + buf][0];

        // ----- tile B -----
        {
            f32x4 pv[4];
            __builtin_amdgcn_s_setprio(1);
#pragma unroll
            for (int nb = 0; nb < 4; ++nb) {
                int row = nb * 16 + lr;
                int x = (row & 7) << 4;
                f32x4 s = {};
                s = __builtin_amdgcn_mfma_f32_16x16x32_bf16(*(const bf16x8*)(ksb + row * 128 + ((g * 16) ^ x)), qfB[0], s, 0, 0, 0);
                s = __builtin_amdgcn_mfma_f32_16x16x32_bf16(*(const bf16x8*)(ksb + row * 128 + ((64 + g * 16) ^ x)), qfB[1], s, 0, 0, 0);
#pragma unroll
                for (int r = 0; r < 4; ++r) {
                    float v = exp2f(fmaf(s[r], C1, -lnB));
                    if (tt == qtB && (nb * 16 + g * 4 + r > qloc)) v = 0.f;
                    pv[nb][r] = v;
                }
            }
            __builtin_amdgcn_s_setprio(0);
#pragma unroll
            for (int nb = 0; nb < 4; ++nb)
                *(f32x4*)(PbaseB + (size_t)qloc * S + tt * 64 + nb * 16 + g * 4) = pv[nb];
#pragma unroll
            for (int nb = 0; nb < 4; ++nb) {
                uint_t w0, w1;
                asm("v_cvt_pk_bf16_f32 %0, %1, %2" : "=v"(w0) : "v"(pv[nb][0]), "v"(pv[nb][1]));
                asm("v_cvt_pk_bf16_f32 %0, %1, %2" : "=v"(w1) : "v"(pv[nb][2]), "v"(pv[nb][3]));
                uint2 w; w.x = w0; w.y = w1;
                *(uint2*)(PlB + ((lr * 128 + nb * 32 + g * 8) ^ ((lr & 7) << 4))) = w;
            }
            __builtin_amdgcn_wave_barrier();
            __builtin_amdgcn_s_setprio(1);
#pragma unroll
            for (int kc = 0; kc < 2; ++kc) {
                bf16x8 pf = *(const bf16x8*)(PlB + ((lr * 128 + kc * 64 + g * 16) ^ ((lr & 7) << 4)));
#pragma unroll
                for (int nb = 0; nb < 4; ++nb) {
                    int vrow = nb * 16 + lr;
                    bf16x8 vf = *(const bf16x8*)(vsb + vrow * 128 + ((kc * 64 + g * 16) ^ ((vrow & 7) << 4)));
                    OB[nb] = __builtin_amdgcn_mfma_f32_16x16x32_bf16(pf, vf, OB[nb], 0, 0, 0);
                }
            }
            __builtin_amdgcn_s_setprio(0);
            __builtin_amdgcn_wave_barrier();
        }

        // ----- tile A (subset range) -----
        if (tt <= qtA) {
            f32x4 pv[4];
            __builtin_amdgcn_s_setprio(1);
#pragma unroll
            for (int nb = 0; nb < 4; ++nb) {
                int row = nb * 16 + lr;
                int x = (row & 7) << 4;
                f32x4 s = {};
                s = __builtin_amdgcn_mfma_f32_16x16x32_bf16(*(const bf16x8*)(ksb + row * 128 + ((g * 16) ^ x)), qfA[0], s, 0, 0, 0);
                s = __builtin_amdgcn_mfma_f32_16x16x32_bf16(*(const bf16x8*)(ksb + row * 128 + ((64 + g * 16) ^ x)), qfA[1], s, 0, 0, 0);
#pragma unroll
                for (int r = 0; r < 4; ++r) {
                    float v = exp2f(fmaf(s[r], C1, -lnA));
                    if (tt == qtA && (nb * 16 + g * 4 + r > qloc)) v = 0.f;
                    pv[nb][r] = v;
                }
            }
            __builtin_amdgcn_s_setprio(0);
#pragma unroll
            for (int nb = 0; nb < 4; ++nb)
                *(f32x4*)(PbaseA + (size_t)qloc * S + tt * 64 + nb * 16 + g * 4) = pv[nb];
#pragma unroll
            for (int nb = 0; nb < 4; ++nb) {
                uint_t w0, w1;
                asm("v_cvt_pk_bf16_f32 %0, %1, %2" : "=v"(w0) : "v"(pv[nb][0]), "v"(pv[nb][1]));
                asm("v_cvt_pk_bf16_f32 %0, %1, %2" : "=v"(w1) : "v"(pv[nb][2]), "v"(pv[nb][3]));
                uint2 w; w.x = w0; w.y = w1;
                *(uint2*)(PlB + ((lr * 128 + nb * 32 + g * 8) ^ ((lr & 7) << 4))) = w;
            }
            __builtin_amdgcn_wave_barrier();
            __builtin_amdgcn_s_setprio(1);
#pragma unroll
            for (int kc = 0; kc < 2; ++kc) {
                bf16x8 pf = *(const bf16x8*)(PlB + ((lr * 128 + kc * 64 + g * 16) ^ ((lr & 7) << 4)));
#pragma unroll
                for (int nb = 0; nb < 4; ++nb) {
                    int vrow = nb * 16 + lr;
                    bf16x8 vf = *(const bf16x8*)(vsb + vrow * 128 + ((kc * 64 + g * 16) ^ ((vrow & 7) << 4)));
                    OA[nb] = __builtin_amdgcn_mfma_f32_16x16x32_bf16(pf, vf, OA[nb], 0, 0, 0);
                }
            }
            __builtin_amdgcn_s_setprio(0);
            __builtin_amdgcn_wave_barrier();
            // drain stage loads (and older zero stores); the 8 newest P stores linger
            asm volatile("s_waitcnt vmcnt(8)" ::: "memory");
        } else {
            asm volatile("s_waitcnt vmcnt(4)" ::: "memory");
        }
        __builtin_amdgcn_s_barrier();
        __builtin_amdgcn_sched_barrier(0);
        buf ^= 1;
    }

    // write O (bf16) as [B,S,H*Dh] for both tiles
#pragma unroll
    for (int nb = 0; nb < 4; ++nb)
#pragma unroll
        for (int r = 0; r < 4; ++r) {
            int qA = qtA * 64 + wid * 16 + g * 4 + r;
            int qB = qtB * 64 + wid * 16 + g * 4 + r;
            Oout[((size_t)b * S + qA) * 1024 + h * 64 + nb * 16 + lr] = f2b(OA[nb][r]);
            Oout[((size_t)b * S + qB) * 1024 + h * 64 + nb * 16 + lr] = f2b(OB[nb][r]);
        }
}

extern "C" void kernel_launch(void* const* d_in, const int* in_sizes, int n_in,
                              void* d_out, int out_size, void* d_ws, size_t ws_size,
                              hipStream_t stream) {
    const float* x  = (const float*)d_in[0];
    const float* Wq = (const float*)d_in[1];
    const float* Wk = (const float*)d_in[2];
    const float* Wv = (const float*)d_in[3];
    const float* Wo = (const float*)d_in[4];
    const float* bo = (const float*)d_in[5];

    float* out  = (float*)d_out;
    float* Pout = out + (size_t)8388608; // attn_probs region

    char* ws = (char*)d_ws;
    ushort_t* xb    = (ushort_t*)(ws);                       // 16 MB
    ushort_t* wqkv  = (ushort_t*)(ws + (16u << 20));         // 6 MB [3072][1024]
    ushort_t* wob   = (ushort_t*)(ws + (22u << 20));         // 2 MB
    ushort_t* Cqkv  = (ushort_t*)(ws + (24u << 20));         // 48 MB [8192][3072]
    ushort_t* Vtw   = (ushort_t*)(ws + (72u << 20));         // 32 MB [b*16+h][64][2048]
    ushort_t* attnb = (ushort_t*)(ws + (104u << 20));        // 16 MB

    // 1. dtype conversions / weight transposes (one launch for all four weights)
    convert_x_kernel<<<8192, 256, 0, stream>>>(x, xb, 2097152);
    transpose_w4_kernel<<<dim3(32, 32, 4), dim3(32, 8), 0, stream>>>(Wq, Wk, Wv, Wo, wqkv, wob);

    // 2. fused QKV projection: Cqkv[8192][3072]
    gemm_kernel<3072, 1><<<dim3(64, 24), 256, 0, stream>>>(xb, wqkv, Cqkv, nullptr, nullptr);

    // 3. V transpose to [b][h][d][s]
    vt_kernel<<<dim3(32, 16, 4), 256, 0, stream>>>(Cqkv, Vtw);

    // 4. attention, paired q-tiles, zero-fill interleaved (R11 best config)
    attn_kernel<<<1024, 256, 0, stream>>>(Cqkv, Vtw, Pout, attnb);

    // 5. output projection + bias (fp32 out)
    gemm_kernel<1024, 0><<<dim3(64, 8), 256, 0, stream>>>(attnb, wob, nullptr, out, bo);
}